// Round 11
// baseline (66.950 us; speedup 1.0000x reference)
//
#include <hip/hip_runtime.h>
#include <cmath>

#define NR 65536
#define DIM 512
#define KC 128
#define NPART 64
#define R_PART (NR / NPART)     // 1024 rows per part
#define NSTEP (R_PART / 32)     // 32 steps of 32 rows
#define NSTRIP 8                // 64-col strips
#define SCOL 64
#define NMAIN (NPART * NSTRIP)  // 512 main blocks

typedef __attribute__((ext_vector_type(8))) short short8v;
typedef __attribute__((ext_vector_type(4))) float f32x4;

union ABu { unsigned w[4]; short8v v; };

// fp32 -> bf16 bits, round-to-nearest-even (inputs finite)
__device__ __forceinline__ unsigned f2bf(float f) {
    const unsigned u = __float_as_uint(f);
    return (u + 0x7FFFu + ((u >> 16) & 1u)) >> 16;
}

// ---------------------------------------------------------------------------
// Kernel A: streaming one-hot MFMA segment sum.
// Main blocks (512 = 64 parts x 8 strips, 256 thr = 4 waves):
//   - X read perfectly coalesced, double-buffered in LDS (32 rows x 64 cols).
//   - per 32-row step: A = onehot(y) built in-register per 16-class tile,
//     B = bf16(X-tile); 8 x mfma_f32_16x16x32_bf16 accumulate all 128
//     classes x 16 cols per wave. k-slot mapping cancels between A and B.
//   - C/D mapping (verified): class = ct*16 + (lane>>4)*4 + reg,
//     col = colbase + 16*wave + (lane&15).
// Count blocks (64, one per part): same A, B = ones -> exact class counts.
// ---------------------------------------------------------------------------
__global__ __launch_bounds__(256, 2) void vmf_mfma_scan(
    const float* __restrict__ X, const int* __restrict__ y,
    float* __restrict__ partial, float* __restrict__ pcountf)
{
    __shared__ float stage[2][32][SCOL];   // 16 KB double buffer
    __shared__ f32x4 cfold[4][8][64];      // 8 KB (count blocks only)

    const int tid  = threadIdx.x;
    const int lane = tid & 63;
    const int w    = tid >> 6;             // wave 0..3
    const int g    = lane >> 4;            // lane group 0..3
    const int lc   = lane & 15;

    f32x4 acc[8];
    #pragma unroll
    for (int ct = 0; ct < 8; ++ct) acc[ct] = (f32x4){0.f, 0.f, 0.f, 0.f};

    if ((int)blockIdx.x >= NMAIN) {
        // ---- count block: B == 1.0, waves split steps, fold at end ----
        const int part = blockIdx.x - NMAIN;
        const int rowbase = part * R_PART;
        ABu bones;
        #pragma unroll
        for (int p = 0; p < 4; ++p) bones.w[p] = 0x3F803F80u;
        for (int s = w; s < NSTEP; s += 4) {
            const int rowb = rowbase + s * 32;
            const int4* yp = (const int4*)(y + rowb + 8 * g);
            const int4 ya = yp[0], yb = yp[1];
            const int yv[8] = {ya.x, ya.y, ya.z, ya.w, yb.x, yb.y, yb.z, yb.w};
            #pragma unroll
            for (int ct = 0; ct < 8; ++ct) {
                ABu a;
                const int cv = ct * 16 + lc;
                #pragma unroll
                for (int p = 0; p < 4; ++p) {
                    const unsigned lo = (yv[2*p]   == cv) ? 0x3F80u     : 0u;
                    const unsigned hi = (yv[2*p+1] == cv) ? 0x3F800000u : 0u;
                    a.w[p] = lo | hi;
                }
                acc[ct] = __builtin_amdgcn_mfma_f32_16x16x32_bf16(
                    a.v, bones.v, acc[ct], 0, 0, 0);
            }
        }
        #pragma unroll
        for (int ct = 0; ct < 8; ++ct) cfold[w][ct][lane] = acc[ct];
        __syncthreads();
        if (tid < KC) {
            const int c = tid, ct = c >> 4, q = (c & 15) >> 2, r = c & 3;
            float v = 0.f;
            #pragma unroll
            for (int w2 = 0; w2 < 4; ++w2) v += cfold[w2][ct][q * 16][r];
            pcountf[part * KC + c] = v;
        }
        return;
    }

    // ---- main block ----
    const int part    = blockIdx.x >> 3;
    const int strip   = blockIdx.x & 7;
    const int rowbase = part * R_PART;
    const int colbase = strip * SCOL;

    const int srow = tid >> 3;             // staging row 0..31
    const int scol = 8 * (tid & 7);        // staging col (8 floats/thread)
    const float* xsrc = X + (size_t)(rowbase + srow) * DIM + colbase + scol;

    float4 pre0 = *(const float4*)xsrc;
    float4 pre1 = *(const float4*)(xsrc + 4);
    { float* sp = &stage[0][srow][scol]; *(float4*)sp = pre0; *(float4*)(sp+4) = pre1; }
    __syncthreads();

    for (int s = 0; s < NSTEP; ++s) {
        const int buf = s & 1;
        if (s + 1 < NSTEP) {               // issue next-step loads early
            const float* ps = xsrc + (size_t)(s + 1) * 32 * DIM;
            pre0 = *(const float4*)ps;
            pre1 = *(const float4*)(ps + 4);
        }
        const int rowb = rowbase + s * 32;
        const int4* yp = (const int4*)(y + rowb + 8 * g);
        const int4 ya = yp[0], yb = yp[1];
        const int yv[8] = {ya.x, ya.y, ya.z, ya.w, yb.x, yb.y, yb.z, yb.w};

        ABu b;                             // B[k][col], k-slot = 8g+j
        #pragma unroll
        for (int p = 0; p < 4; ++p) {
            const float f0 = stage[buf][8*g + 2*p    ][16*w + lc];
            const float f1 = stage[buf][8*g + 2*p + 1][16*w + lc];
            b.w[p] = f2bf(f0) | (f2bf(f1) << 16);
        }
        #pragma unroll
        for (int ct = 0; ct < 8; ++ct) {   // A one-hot per 16-class tile
            ABu a;
            const int cv = ct * 16 + lc;
            #pragma unroll
            for (int p = 0; p < 4; ++p) {
                const unsigned lo = (yv[2*p]   == cv) ? 0x3F80u     : 0u;
                const unsigned hi = (yv[2*p+1] == cv) ? 0x3F800000u : 0u;
                a.w[p] = lo | hi;
            }
            acc[ct] = __builtin_amdgcn_mfma_f32_16x16x32_bf16(
                a.v, b.v, acc[ct], 0, 0, 0);
        }
        if (s + 1 < NSTEP) {               // write next step to other buffer
            float* sp = &stage[buf ^ 1][srow][scol];
            *(float4*)sp = pre0; *(float4*)(sp + 4) = pre1;
        }
        __syncthreads();
    }

    // write: class = ct*16 + g*4 + r, col = colbase + 16w + lc
    #pragma unroll
    for (int ct = 0; ct < 8; ++ct) {
        #pragma unroll
        for (int r = 0; r < 4; ++r) {
            const int c = ct * 16 + g * 4 + r;
            partial[((size_t)part * KC + c) * DIM + colbase + 16 * w + lc] =
                acc[ct][r];
        }
    }
}

// ---------------------------------------------------------------------------
// Kernel B: fold 64 part-partials -> r[K][D]; norm, kappa, logk, ive.
// ---------------------------------------------------------------------------
__global__ __launch_bounds__(512) void vmf_reduce2(
    const float* __restrict__ partial, const float* __restrict__ pcountf,
    float* __restrict__ r, float* __restrict__ kappa, float* __restrict__ logk,
    float* __restrict__ bes, float* __restrict__ innorm)
{
    const int k = blockIdx.x, t = threadIdx.x;
    float s = 0.f;
    for (int hh = 0; hh < NPART; ++hh)
        s += partial[(size_t)(hh * KC + k) * DIM + t];
    r[(size_t)k * DIM + t] = s;

    float ss = s * s;
    for (int off = 32; off; off >>= 1) ss += __shfl_down(ss, off);
    __shared__ float wsum[8];
    if ((t & 63) == 0) wsum[t >> 6] = ss;
    __syncthreads();
    if (t == 0) {
        float tot = 0.f;
        #pragma unroll
        for (int q = 0; q < 8; ++q) tot += wsum[q];
        const float norm = sqrtf(tot);
        float nk = 0.f;
        for (int hh = 0; hh < NPART; ++hh) nk += pcountf[hh * KC + k];
        const float rb = norm / nk;
        float kap = ((float)DIM * rb - rb * rb * rb) / (1.f - rb * rb);
        if (rb > 0.9f) kap = -0.4f + 1.39f * rb + 0.43f / (1.f - rb);
        kappa[k] = kap;
        logk[k]  = logf(kap);
        const float v  = 255.5f;
        const float zz = kap / v;
        const float sq = sqrtf(1.f + zz * zz);
        const float tt = 1.f / sq, t2 = tt * tt;
        const float eta = sq + logf(zz / (1.f + sq));
        const float u1 = (3.f * tt - 5.f * tt * t2) / 24.f;
        const float u2 = (81.f * t2 - 462.f * t2 * t2 + 385.f * t2 * t2 * t2) / 1152.f;
        const float u3 = (30375.f * tt * t2 - 369603.f * tt * t2 * t2
                    + 765765.f * tt * t2 * t2 * t2
                    - 425425.f * tt * t2 * t2 * t2 * t2) / 414720.f;
        const float series = 1.f + u1 / v + u2 / (v * v) + u3 / (v * v * v);
        const float ive = expf(v * eta - kap) * series
                    / (sqrtf(2.f * 3.14159265358979f * v) * sqrtf(sq));
        bes[k] = ive;
        innorm[k] = 1.f / norm;
    }
}

// ---------------------------------------------------------------------------
// Kernel C: block i computes kl[i][j]^2 for all j, reduces to rowsum[i].
// ---------------------------------------------------------------------------
__global__ __launch_bounds__(128) void vmf_gram(
    const float* __restrict__ r, const float* __restrict__ kappa,
    const float* __restrict__ logk, const float* __restrict__ bes,
    const float* __restrict__ innorm, float* __restrict__ rowsum)
{
    const int i = blockIdx.x, j = threadIdx.x;
    __shared__ float mui[DIM];
    const float inv_i = innorm[i];
    for (int d = j; d < DIM; d += 128) mui[d] = r[(size_t)i * DIM + d] * inv_i;
    __syncthreads();

    const float4* rj = (const float4*)(r + (size_t)j * DIM);
    float acc = 0.f;
    #pragma unroll 4
    for (int d4 = 0; d4 < DIM / 4; ++d4) {
        float4 v = rj[d4];
        acc += mui[d4 * 4 + 0] * v.x + mui[d4 * 4 + 1] * v.y
             + mui[d4 * 4 + 2] * v.z + mui[d4 * 4 + 3] * v.w;
    }
    const float dot = acc * innorm[j];
    const float dstar = 255.5f;
    float kl = dstar * (logk[j] - logk[i]) - kappa[i] + bes[i] - bes[j]
             + kappa[j] * dot;
    float v2 = kl * kl;
    for (int off = 32; off; off >>= 1) v2 += __shfl_down(v2, off);
    __shared__ float ws2[2];
    if ((j & 63) == 0) ws2[j >> 6] = v2;
    __syncthreads();
    if (j == 0) rowsum[i] = ws2[0] + ws2[1];
}

// ---------------------------------------------------------------------------
// Kernel D: sum 128 row sums -> out[0] = total / K^2
// ---------------------------------------------------------------------------
__global__ __launch_bounds__(128) void vmf_final(
    const float* __restrict__ rowsum, float* __restrict__ out)
{
    const int t = threadIdx.x;
    float v = rowsum[t];
    for (int off = 32; off; off >>= 1) v += __shfl_down(v, off);
    __shared__ float w[2];
    if ((t & 63) == 0) w[t >> 6] = v;
    __syncthreads();
    if (t == 0) out[0] = (w[0] + w[1]) / (float)(KC * KC);
}

extern "C" void kernel_launch(void* const* d_in, const int* in_sizes, int n_in,
                              void* d_out, int out_size, void* d_ws, size_t ws_size,
                              hipStream_t stream)
{
    const float* X = (const float*)d_in[0];
    const int*   y = (const int*)d_in[1];
    float* out = (float*)d_out;
    float* ws  = (float*)d_ws;

    // workspace layout (float units)
    float* r       = ws;                    // 0      .. 65535
    float* kappa   = ws + 65536;            // 65536  .. 65663
    float* logk    = ws + 65536 + 128;      // 65664  .. 65791
    float* bes     = ws + 65536 + 256;      // 65792  .. 65919
    float* innorm  = ws + 65536 + 384;      // 65920  .. 66047
    float* rowsum  = ws + 65536 + 512;      // 66048  .. 66175
    float* pcountf = ws + 66176;            // 66176  .. 74367 (64*128)
    float* partial = ws + 74368;            // 74368  .. +4194304 (16 MB)

    vmf_mfma_scan<<<NMAIN + NPART, 256, 0, stream>>>(X, y, partial, pcountf);
    vmf_reduce2<<<KC, 512, 0, stream>>>(partial, pcountf, r, kappa, logk, bes,
                                        innorm);
    vmf_gram<<<KC, 128, 0, stream>>>(r, kappa, logk, bes, innorm, rowsum);
    vmf_final<<<1, 128, 0, stream>>>(rowsum, out);
}

// Round 12
// 63.109 us; speedup vs baseline: 1.0609x; 1.0609x over previous
//
#include <hip/hip_runtime.h>
#include <cmath>

#define NR 65536
#define DIM 512
#define KC 128
#define NPART 128
#define R_PART (NR / NPART)     // 512 rows per part
#define NSTEP (R_PART / 32)     // 16 steps of 32 rows
#define NSTRIP 8                // 64-col strips
#define SCOL 64
#define NMAIN (NPART * NSTRIP)  // 1024 main blocks

typedef __attribute__((ext_vector_type(8))) short short8v;
typedef __attribute__((ext_vector_type(4))) float f32x4;

union ABu { unsigned w[4]; short8v v; };

// packed f32x2 -> bf16x2 (RTNE), single instruction (no builtin on gfx950)
__device__ __forceinline__ unsigned cvt_pk_bf16(float lo, float hi) {
    unsigned r;
    asm("v_cvt_pk_bf16_f32 %0, %1, %2" : "=v"(r) : "v"(lo), "v"(hi));
    return r;
}

// ---------------------------------------------------------------------------
// Kernel A: barrier-free streaming one-hot MFMA segment sum.
// Main blocks (1024 = 128 parts x 8 strips, 256 thr = 4 waves, no LDS,
// no barriers): per 32-row step each wave
//   - loads its B-fragment column directly from global (8 f32, 64B-coalesced
//     per 16-lane group; register-double-buffered one step ahead),
//   - packs to bf16 via v_cvt_pk_bf16_f32,
//   - builds one-hot A from y in registers (v1-proven mapping),
//   - 8 x mfma_f32_16x16x32_bf16 -> all 128 classes for its 16 cols.
// A/B use the same k-slot convention so any HW k-permutation cancels
// (validated end-to-end in R11, absmax 0.0).
// Count blocks (128, one per part): same A, B = ones -> exact counts.
// ---------------------------------------------------------------------------
__global__ __launch_bounds__(256, 4) void vmf_mfma_scan(
    const float* __restrict__ X, const int* __restrict__ y,
    float* __restrict__ partial, float* __restrict__ pcountf)
{
    __shared__ f32x4 cfold[4][8][64];      // used by count blocks only (8 KB)

    const int tid  = threadIdx.x;
    const int lane = tid & 63;
    const int w    = tid >> 6;             // wave 0..3
    const int g    = lane >> 4;            // lane group 0..3
    const int lc   = lane & 15;

    f32x4 acc[8];
    #pragma unroll
    for (int ct = 0; ct < 8; ++ct) acc[ct] = (f32x4){0.f, 0.f, 0.f, 0.f};

    if ((int)blockIdx.x >= NMAIN) {
        // ---- count block: B == 1.0, waves split steps, fold at end ----
        const int part = blockIdx.x - NMAIN;
        const int rowbase = part * R_PART;
        ABu bones;
        #pragma unroll
        for (int p = 0; p < 4; ++p) bones.w[p] = 0x3F803F80u;
        for (int s = w; s < NSTEP; s += 4) {
            const int rowb = rowbase + s * 32;
            const int4* yp = (const int4*)(y + rowb + 8 * g);
            const int4 ya = yp[0], yb = yp[1];
            const int yv[8] = {ya.x, ya.y, ya.z, ya.w, yb.x, yb.y, yb.z, yb.w};
            #pragma unroll
            for (int ct = 0; ct < 8; ++ct) {
                ABu a;
                const int cv = ct * 16 + lc;
                #pragma unroll
                for (int p = 0; p < 4; ++p) {
                    const unsigned lo = (yv[2*p]   == cv) ? 0x3F80u     : 0u;
                    const unsigned hi = (yv[2*p+1] == cv) ? 0x3F800000u : 0u;
                    a.w[p] = lo | hi;
                }
                acc[ct] = __builtin_amdgcn_mfma_f32_16x16x32_bf16(
                    a.v, bones.v, acc[ct], 0, 0, 0);
            }
        }
        #pragma unroll
        for (int ct = 0; ct < 8; ++ct) cfold[w][ct][lane] = acc[ct];
        __syncthreads();
        if (tid < KC) {
            const int c = tid, ct = c >> 4, q = (c & 15) >> 2, r = c & 3;
            float v = 0.f;
            #pragma unroll
            for (int w2 = 0; w2 < 4; ++w2) v += cfold[w2][ct][q * 16][r];
            pcountf[part * KC + c] = v;
        }
        return;
    }

    // ---- main block ----
    const int part    = blockIdx.x >> 3;
    const int strip   = blockIdx.x & 7;
    const int rowbase = part * R_PART;
    const int col     = strip * SCOL + 16 * w + lc;   // this lane's column
    const float* xcol = X + col;

    // preload step-0 B floats (rows rowbase + 8g + j)
    float bf[8];
    #pragma unroll
    for (int j = 0; j < 8; ++j)
        bf[j] = xcol[(size_t)(rowbase + 8 * g + j) * DIM];

    for (int s = 0; s < NSTEP; ++s) {
        const int rowb = rowbase + s * 32;

        // issue next-step loads first (independent of this step's MFMAs)
        float bn[8];
        if (s + 1 < NSTEP) {
            #pragma unroll
            for (int j = 0; j < 8; ++j)
                bn[j] = xcol[(size_t)(rowb + 32 + 8 * g + j) * DIM];
        }

        const int4* yp = (const int4*)(y + rowb + 8 * g);
        const int4 ya = yp[0], yb = yp[1];
        const int yv[8] = {ya.x, ya.y, ya.z, ya.w, yb.x, yb.y, yb.z, yb.w};

        ABu b;                             // B[k][col], k-slot = 8g + j
        #pragma unroll
        for (int p = 0; p < 4; ++p)
            b.w[p] = cvt_pk_bf16(bf[2*p], bf[2*p + 1]);

        #pragma unroll
        for (int ct = 0; ct < 8; ++ct) {   // A one-hot per 16-class tile
            ABu a;
            const int cv = ct * 16 + lc;
            #pragma unroll
            for (int p = 0; p < 4; ++p) {
                const unsigned lo = (yv[2*p]   == cv) ? 0x3F80u     : 0u;
                const unsigned hi = (yv[2*p+1] == cv) ? 0x3F800000u : 0u;
                a.w[p] = lo | hi;
            }
            acc[ct] = __builtin_amdgcn_mfma_f32_16x16x32_bf16(
                a.v, b.v, acc[ct], 0, 0, 0);
        }

        if (s + 1 < NSTEP) {
            #pragma unroll
            for (int j = 0; j < 8; ++j) bf[j] = bn[j];
        }
    }

    // write: class = ct*16 + g*4 + r at this lane's col (verified C/D map)
    #pragma unroll
    for (int ct = 0; ct < 8; ++ct) {
        #pragma unroll
        for (int r = 0; r < 4; ++r) {
            const int c = ct * 16 + g * 4 + r;
            partial[((size_t)part * KC + c) * DIM + col] = acc[ct][r];
        }
    }
}

// ---------------------------------------------------------------------------
// Kernel B: fold 128 part-partials -> r[K][D]; norm, kappa, logk, ive.
// ---------------------------------------------------------------------------
__global__ __launch_bounds__(512) void vmf_reduce2(
    const float* __restrict__ partial, const float* __restrict__ pcountf,
    float* __restrict__ r, float* __restrict__ kappa, float* __restrict__ logk,
    float* __restrict__ bes, float* __restrict__ innorm)
{
    const int k = blockIdx.x, t = threadIdx.x;
    float s = 0.f;
    for (int hh = 0; hh < NPART; ++hh)
        s += partial[(size_t)(hh * KC + k) * DIM + t];
    r[(size_t)k * DIM + t] = s;

    float ss = s * s;
    for (int off = 32; off; off >>= 1) ss += __shfl_down(ss, off);
    __shared__ float wsum[8];
    if ((t & 63) == 0) wsum[t >> 6] = ss;
    __syncthreads();
    if (t == 0) {
        float tot = 0.f;
        #pragma unroll
        for (int q = 0; q < 8; ++q) tot += wsum[q];
        const float norm = sqrtf(tot);
        float nk = 0.f;
        for (int hh = 0; hh < NPART; ++hh) nk += pcountf[hh * KC + k];
        const float rb = norm / nk;
        float kap = ((float)DIM * rb - rb * rb * rb) / (1.f - rb * rb);
        if (rb > 0.9f) kap = -0.4f + 1.39f * rb + 0.43f / (1.f - rb);
        kappa[k] = kap;
        logk[k]  = logf(kap);
        const float v  = 255.5f;
        const float zz = kap / v;
        const float sq = sqrtf(1.f + zz * zz);
        const float tt = 1.f / sq, t2 = tt * tt;
        const float eta = sq + logf(zz / (1.f + sq));
        const float u1 = (3.f * tt - 5.f * tt * t2) / 24.f;
        const float u2 = (81.f * t2 - 462.f * t2 * t2 + 385.f * t2 * t2 * t2) / 1152.f;
        const float u3 = (30375.f * tt * t2 - 369603.f * tt * t2 * t2
                    + 765765.f * tt * t2 * t2 * t2
                    - 425425.f * tt * t2 * t2 * t2 * t2) / 414720.f;
        const float series = 1.f + u1 / v + u2 / (v * v) + u3 / (v * v * v);
        const float ive = expf(v * eta - kap) * series
                    / (sqrtf(2.f * 3.14159265358979f * v) * sqrtf(sq));
        bes[k] = ive;
        innorm[k] = 1.f / norm;
    }
}

// ---------------------------------------------------------------------------
// Kernel C: block i computes kl[i][j]^2 for all j, reduces to rowsum[i].
// ---------------------------------------------------------------------------
__global__ __launch_bounds__(128) void vmf_gram(
    const float* __restrict__ r, const float* __restrict__ kappa,
    const float* __restrict__ logk, const float* __restrict__ bes,
    const float* __restrict__ innorm, float* __restrict__ rowsum)
{
    const int i = blockIdx.x, j = threadIdx.x;
    __shared__ float mui[DIM];
    const float inv_i = innorm[i];
    for (int d = j; d < DIM; d += 128) mui[d] = r[(size_t)i * DIM + d] * inv_i;
    __syncthreads();

    const float4* rj = (const float4*)(r + (size_t)j * DIM);
    float acc = 0.f;
    #pragma unroll 4
    for (int d4 = 0; d4 < DIM / 4; ++d4) {
        float4 v = rj[d4];
        acc += mui[d4 * 4 + 0] * v.x + mui[d4 * 4 + 1] * v.y
             + mui[d4 * 4 + 2] * v.z + mui[d4 * 4 + 3] * v.w;
    }
    const float dot = acc * innorm[j];
    const float dstar = 255.5f;
    float kl = dstar * (logk[j] - logk[i]) - kappa[i] + bes[i] - bes[j]
             + kappa[j] * dot;
    float v2 = kl * kl;
    for (int off = 32; off; off >>= 1) v2 += __shfl_down(v2, off);
    __shared__ float ws2[2];
    if ((j & 63) == 0) ws2[j >> 6] = v2;
    __syncthreads();
    if (j == 0) rowsum[i] = ws2[0] + ws2[1];
}

// ---------------------------------------------------------------------------
// Kernel D: sum 128 row sums -> out[0] = total / K^2
// ---------------------------------------------------------------------------
__global__ __launch_bounds__(128) void vmf_final(
    const float* __restrict__ rowsum, float* __restrict__ out)
{
    const int t = threadIdx.x;
    float v = rowsum[t];
    for (int off = 32; off; off >>= 1) v += __shfl_down(v, off);
    __shared__ float w[2];
    if ((t & 63) == 0) w[t >> 6] = v;
    __syncthreads();
    if (t == 0) out[0] = (w[0] + w[1]) / (float)(KC * KC);
}

extern "C" void kernel_launch(void* const* d_in, const int* in_sizes, int n_in,
                              void* d_out, int out_size, void* d_ws, size_t ws_size,
                              hipStream_t stream)
{
    const float* X = (const float*)d_in[0];
    const int*   y = (const int*)d_in[1];
    float* out = (float*)d_out;
    float* ws  = (float*)d_ws;

    // workspace layout (float units)
    float* r       = ws;                    // 0      .. 65535
    float* kappa   = ws + 65536;            // 65536  .. 65663
    float* logk    = ws + 65536 + 128;      // 65664  .. 65791
    float* bes     = ws + 65536 + 256;      // 65792  .. 65919
    float* innorm  = ws + 65536 + 384;      // 65920  .. 66047
    float* rowsum  = ws + 65536 + 512;      // 66048  .. 66175
    float* pcountf = ws + 66176;            // 66176  .. 82559 (128*128)
    float* partial = ws + 82944;            // 82944  .. +33554432B (32 MB)

    vmf_mfma_scan<<<NMAIN + NPART, 256, 0, stream>>>(X, y, partial, pcountf);
    vmf_reduce2<<<KC, 512, 0, stream>>>(partial, pcountf, r, kappa, logk, bes,
                                        innorm);
    vmf_gram<<<KC, 128, 0, stream>>>(r, kappa, logk, bes, innorm, rowsum);
    vmf_final<<<1, 128, 0, stream>>>(rowsum, out);
}